// Round 5
// baseline (217.336 us; speedup 1.0000x reference)
//
#include <hip/hip_runtime.h>
#include <math.h>

#define N_NODES 4096
#define DIM 256
#define HEADS 4
#define HDIM 64
#define NEDGE 131072
#define MAXNBR 256
#define MASK_WORDS 128   // 4096 / 32
#define CSR_ROWS 32      // rows per block in fused CSR kernel

typedef __attribute__((ext_vector_type(8))) short short8;
typedef __attribute__((ext_vector_type(4))) float float4v;

__device__ inline unsigned short f2b(float f) {   // fp32 -> bf16 RNE
    unsigned u = __float_as_uint(f);
    unsigned r = u + 0x7fffu + ((u >> 16) & 1u);
    return (unsigned short)(r >> 16);
}
__device__ inline float b2f(unsigned short s) { return __uint_as_float(((unsigned)s) << 16); }
__device__ inline float bl(unsigned u) { return __uint_as_float(u << 16); }
__device__ inline float bh(unsigned u) { return __uint_as_float(u & 0xffff0000u); }

__device__ inline uint4 pack8(float4 a, float4 b) {
    uint4 w;
    w.x = (unsigned)f2b(a.x) | ((unsigned)f2b(a.y) << 16);
    w.y = (unsigned)f2b(a.z) | ((unsigned)f2b(a.w) << 16);
    w.z = (unsigned)f2b(b.x) | ((unsigned)f2b(b.y) << 16);
    w.w = (unsigned)f2b(b.z) | ((unsigned)f2b(b.w) << 16);
    return w;
}

// ---------------- fused CSR build: LDS bitmask per 32-row slice ----------------
// 128 blocks x 256 threads. Each block owns rows [b*32, b*32+32), scans all edges
// (uint4 = 4 edges/lane/iter), sets bits in a 16 KB LDS mask, then extracts CSR.
__global__ __launch_bounds__(256)
void csr_fused_kernel(const int* __restrict__ eidx,
                      int* __restrict__ nnz, int* __restrict__ cols) {
    __shared__ unsigned int umask[CSR_ROWS * MASK_WORDS];   // 16 KB
    const int tid = threadIdx.x;
    const int r0 = blockIdx.x * CSR_ROWS;

    // zero + diag
    for (int w = tid; w < CSR_ROWS * MASK_WORDS; w += 256) umask[w] = 0u;
    __syncthreads();
    if (tid < CSR_ROWS) {
        int g = r0 + tid;
        atomicOr(&umask[tid * MASK_WORDS + (g >> 5)], 1u << (g & 31));
    }
    __syncthreads();

    // edge scan: 4 edges per thread per iter
    const int* srcp = eidx;
    const int* dstp = eidx + NEDGE;
    for (int base = tid * 4; base < NEDGE; base += 256 * 4) {
        uint4 s4 = *(const uint4*)&srcp[base];
        uint4 d4 = *(const uint4*)&dstp[base];
        int ss[4] = {(int)s4.x, (int)s4.y, (int)s4.z, (int)s4.w};
        int dd[4] = {(int)d4.x, (int)d4.y, (int)d4.z, (int)d4.w};
#pragma unroll
        for (int q = 0; q < 4; ++q) {
            int s = ss[q], d = dd[q];
            if ((unsigned)(s - r0) < CSR_ROWS)
                atomicOr(&umask[(s - r0) * MASK_WORDS + (d >> 5)], 1u << (d & 31));
            if ((unsigned)(d - r0) < CSR_ROWS)
                atomicOr(&umask[(d - r0) * MASK_WORDS + (s >> 5)], 1u << (s & 31));
        }
    }
    __syncthreads();

    // extraction: wave w handles rows [w*8, w*8+8)
    const int wave = tid >> 6;
    const int lane = tid & 63;
    for (int rr = wave * 8; rr < wave * 8 + 8; ++rr) {
        const unsigned int* row = &umask[rr * MASK_WORDS];
        unsigned w0 = row[lane * 2];
        unsigned w1 = row[lane * 2 + 1];
        int cnt = __popc(w0) + __popc(w1);
        int incl = cnt;
#pragma unroll
        for (int off = 1; off < 64; off <<= 1) {
            int v = __shfl_up(incl, off, 64);
            if (lane >= off) incl += v;
        }
        int c = incl - cnt;
        int total = __shfl(incl, 63, 64);
        int gr = r0 + rr;
        while (w0) {
            int b = __ffs(w0) - 1;
            if (c < MAXNBR) cols[(size_t)gr * MAXNBR + c] = lane * 64 + b;
            ++c; w0 &= w0 - 1u;
        }
        while (w1) {
            int b = __ffs(w1) - 1;
            if (c < MAXNBR) cols[(size_t)gr * MAXNBR + c] = lane * 64 + 32 + b;
            ++c; w1 &= w1 - 1u;
        }
        if (lane == 0) nnz[gr] = total > MAXNBR ? MAXNBR : total;
    }
}

// ---------------- Wc = W_p @ W_out, bc = W_p@b_out + b_p (4-way ILP) ----------------
__global__ __launch_bounds__(256)
void wc_kernel(const float* __restrict__ wp, const float* __restrict__ wout,
               const float* __restrict__ bout, const float* __restrict__ bp,
               unsigned short* __restrict__ wc, float* __restrict__ bc) {
    const int j = blockIdx.x * 16 + threadIdx.x;
    const int i = blockIdx.y * 16 + threadIdx.y;
    float a0 = 0.f, a1 = 0.f, a2 = 0.f, a3 = 0.f;
    for (int k = 0; k < 256; k += 4) {
        a0 = fmaf(wp[i * 256 + k + 0], wout[(k + 0) * 256 + j], a0);
        a1 = fmaf(wp[i * 256 + k + 1], wout[(k + 1) * 256 + j], a1);
        a2 = fmaf(wp[i * 256 + k + 2], wout[(k + 2) * 256 + j], a2);
        a3 = fmaf(wp[i * 256 + k + 3], wout[(k + 3) * 256 + j], a3);
    }
    wc[i * 256 + j] = f2b((a0 + a1) + (a2 + a3));
    if (blockIdx.x == 0 && blockIdx.y == 0) {
        int t = threadIdx.y * 16 + threadIdx.x;
        float b0 = bp[t], b1 = 0.f, b2 = 0.f, b3 = 0.f;
        for (int k = 0; k < 256; k += 4) {
            b0 = fmaf(wp[t * 256 + k + 0], bout[k + 0], b0);
            b1 = fmaf(wp[t * 256 + k + 1], bout[k + 1], b1);
            b2 = fmaf(wp[t * 256 + k + 2], bout[k + 2], b2);
            b3 = fmaf(wp[t * 256 + k + 3], bout[k + 3], b3);
        }
        bc[t] = (b0 + b1) + (b2 + b3);
    }
}

// ---------------- bf16 MFMA GEMM:  C[M][Nc] = A[M][K] x B[Nc][K]^T + bias (+resid) ----
// BM=BN=128, BK=64, 4 waves (2x2 of 64x64). A and/or B may be fp32 (convert in staging).
template <bool A_F32, bool B_F32, bool OUT_BF16>
__global__ __launch_bounds__(256)
void mfma_gemm_bt(const void* __restrict__ Ain, const void* __restrict__ Bin,
                  const float* __restrict__ bias, const float* __restrict__ resid,
                  void* __restrict__ Cout, int M, int Nc, int K) {
    __shared__ unsigned short As[128 * 64];
    __shared__ unsigned short Bs[128 * 64];
    const int tid  = threadIdx.x;
    const int lane = tid & 63;
    const int wave = tid >> 6;
    const int wm = wave & 1;
    const int wn = wave >> 1;
    const int brow = blockIdx.y * 128;
    const int bcol = blockIdx.x * 128;

    float4v acc[16];
#pragma unroll
    for (int t = 0; t < 16; ++t) acc[t] = (float4v){0.f, 0.f, 0.f, 0.f};

    const int quad = lane >> 4;
    const int l16  = lane & 15;

    for (int k0 = 0; k0 < K; k0 += 64) {
        __syncthreads();
#pragma unroll
        for (int it = 0; it < 4; ++it) {
            int c = it * 256 + tid;
            int row = c >> 3;
            int col = c & 7;
            int sw  = col ^ (row & 7);
            uint4 va, vb;
            if (A_F32) {
                const float* Af = (const float*)Ain;
                float4 x0 = *(const float4*)&Af[(size_t)(brow + row) * K + k0 + col * 8];
                float4 x1 = *(const float4*)&Af[(size_t)(brow + row) * K + k0 + col * 8 + 4];
                va = pack8(x0, x1);
            } else {
                va = *(const uint4*)&((const unsigned short*)Ain)[(size_t)(brow + row) * K + k0 + col * 8];
            }
            if (B_F32) {
                const float* Bf = (const float*)Bin;
                float4 x0 = *(const float4*)&Bf[(size_t)(bcol + row) * K + k0 + col * 8];
                float4 x1 = *(const float4*)&Bf[(size_t)(bcol + row) * K + k0 + col * 8 + 4];
                vb = pack8(x0, x1);
            } else {
                vb = *(const uint4*)&((const unsigned short*)Bin)[(size_t)(bcol + row) * K + k0 + col * 8];
            }
            *(uint4*)&As[row * 64 + sw * 8] = va;
            *(uint4*)&Bs[row * 64 + sw * 8] = vb;
        }
        __syncthreads();
#pragma unroll
        for (int kk = 0; kk < 2; ++kk) {
            short8 af[4], bf[4];
#pragma unroll
            for (int mt = 0; mt < 4; ++mt) {
                int row = wm * 64 + mt * 16 + l16;
                int sw = (kk * 4 + quad) ^ (row & 7);
                af[mt] = *(const short8*)&As[row * 64 + sw * 8];
            }
#pragma unroll
            for (int nt = 0; nt < 4; ++nt) {
                int row = wn * 64 + nt * 16 + l16;
                int sw = (kk * 4 + quad) ^ (row & 7);
                bf[nt] = *(const short8*)&Bs[row * 64 + sw * 8];
            }
#pragma unroll
            for (int mt = 0; mt < 4; ++mt)
#pragma unroll
                for (int nt = 0; nt < 4; ++nt)
                    acc[mt * 4 + nt] = __builtin_amdgcn_mfma_f32_16x16x32_bf16(
                        af[mt], bf[nt], acc[mt * 4 + nt], 0, 0, 0);
        }
    }

#pragma unroll
    for (int mt = 0; mt < 4; ++mt) {
#pragma unroll
        for (int nt = 0; nt < 4; ++nt) {
            int colg = bcol + wn * 64 + nt * 16 + l16;
            float bsv = bias[colg];
#pragma unroll
            for (int reg = 0; reg < 4; ++reg) {
                int rowg = brow + wm * 64 + mt * 16 + quad * 4 + reg;
                float v = acc[mt * 4 + nt][reg] + bsv;
                if (resid) v += resid[(size_t)rowg * Nc + colg];
                if (OUT_BF16)
                    ((unsigned short*)Cout)[(size_t)rowg * Nc + colg] = f2b(v);
                else
                    ((float*)Cout)[(size_t)rowg * Nc + colg] = v;
            }
        }
    }
}

// ---------------- single-pass sparse attention (bf16 qkv) ----------------
// Block per query row i; wave = head. lane = (ng 0..7, dg 0..7): 8-lane clusters
// cooperatively process neighbor t0+ng; dg indexes 8-dim octets (16B loads).
// No max-subtraction (|scores| <~ 6, exp safe in fp32): unnormalized accumulate.
__global__ __launch_bounds__(256)
void attn_sparse_kernel(const unsigned short* __restrict__ qkv, const int* __restrict__ cols,
                        const int* __restrict__ nnz, unsigned short* __restrict__ ctx) {
    __shared__ int cols_s[MAXNBR];

    const int wave = threadIdx.x >> 6;   // head
    const int lane = threadIdx.x & 63;
    const int ng = lane >> 3;
    const int dg = lane & 7;
    const int i = blockIdx.x;
    const int h = wave;

    cols_s[threadIdx.x] = cols[(size_t)i * MAXNBR + threadIdx.x];
    int count = nnz[i];
    if (count > MAXNBR) count = MAXNBR;

    // preload q[h][dg*8 .. dg*8+7] into 8 regs
    float qf[8];
    {
        uint4 qv = *(const uint4*)&qkv[(size_t)i * 768 + h * HDIM + dg * 8];
        qf[0] = bl(qv.x); qf[1] = bh(qv.x);
        qf[2] = bl(qv.y); qf[3] = bh(qv.y);
        qf[4] = bl(qv.z); qf[5] = bh(qv.z);
        qf[6] = bl(qv.w); qf[7] = bh(qv.w);
    }
    __syncthreads();

    const unsigned short* kB = qkv + DIM + h * HDIM + dg * 8;      // K base
    const unsigned short* vB = qkv + 2 * DIM + h * HDIM + dg * 8;  // V base
    float a0 = 0.f, a1 = 0.f, a2 = 0.f, a3 = 0.f, a4 = 0.f, a5 = 0.f, a6 = 0.f, a7 = 0.f;
    float esum = 0.f;

    for (int t0 = 0; t0 < count; t0 += 8) {
        int t = t0 + ng;
        int j = cols_s[min(t, count - 1)];
        uint4 kv = *(const uint4*)&kB[(size_t)j * 768];
        uint4 vv = *(const uint4*)&vB[(size_t)j * 768];
        float s = qf[0] * bl(kv.x) + qf[1] * bh(kv.x)
                + qf[2] * bl(kv.y) + qf[3] * bh(kv.y)
                + qf[4] * bl(kv.z) + qf[5] * bh(kv.z)
                + qf[6] * bl(kv.w) + qf[7] * bh(kv.w);
        // reduce partial dot over dg bits (0,1,2) -> full 64-dim dot, all lanes
        s += __shfl_xor(s, 1, 64);
        s += __shfl_xor(s, 2, 64);
        s += __shfl_xor(s, 4, 64);
        float e = (t < count) ? expf(s * 0.125f) : 0.f;
        esum += e;
        a0 = fmaf(e, bl(vv.x), a0); a1 = fmaf(e, bh(vv.x), a1);
        a2 = fmaf(e, bl(vv.y), a2); a3 = fmaf(e, bh(vv.y), a3);
        a4 = fmaf(e, bl(vv.z), a4); a5 = fmaf(e, bh(vv.z), a5);
        a6 = fmaf(e, bl(vv.w), a6); a7 = fmaf(e, bh(vv.w), a7);
    }
    // reduce across neighbor-groups (lane bits 3,4,5)
#pragma unroll
    for (int off = 8; off <= 32; off <<= 1) {
        esum += __shfl_xor(esum, off, 64);
        a0 += __shfl_xor(a0, off, 64); a1 += __shfl_xor(a1, off, 64);
        a2 += __shfl_xor(a2, off, 64); a3 += __shfl_xor(a3, off, 64);
        a4 += __shfl_xor(a4, off, 64); a5 += __shfl_xor(a5, off, 64);
        a6 += __shfl_xor(a6, off, 64); a7 += __shfl_xor(a7, off, 64);
    }
    if (ng == 0) {
        float inv = 1.0f / esum;
        uint4 w;
        w.x = (unsigned)f2b(a0 * inv) | ((unsigned)f2b(a1 * inv) << 16);
        w.y = (unsigned)f2b(a2 * inv) | ((unsigned)f2b(a3 * inv) << 16);
        w.z = (unsigned)f2b(a4 * inv) | ((unsigned)f2b(a5 * inv) << 16);
        w.w = (unsigned)f2b(a6 * inv) | ((unsigned)f2b(a7 * inv) << 16);
        *(uint4*)&ctx[(size_t)i * DIM + h * HDIM + dg * 8] = w;
    }
}

// ---------------- LayerNorm ----------------
__global__ __launch_bounds__(256)
void ln_kernel(const float* __restrict__ y, const float* __restrict__ gamma,
               const float* __restrict__ beta, float* __restrict__ out) {
    const int wave = threadIdx.x >> 6;
    const int lane = threadIdx.x & 63;
    const int i = blockIdx.x * 4 + wave;
    float4 v = ((const float4*)(y + (size_t)i * DIM))[lane];
    float s = v.x + v.y + v.z + v.w;
    float ss = v.x * v.x + v.y * v.y + v.z * v.z + v.w * v.w;
#pragma unroll
    for (int off = 32; off > 0; off >>= 1) {
        s += __shfl_xor(s, off, 64);
        ss += __shfl_xor(ss, off, 64);
    }
    float mean = s * (1.f / 256.f);
    float var = ss * (1.f / 256.f) - mean * mean;
    float rstd = rsqrtf(var + 1e-5f);
    float4 g = ((const float4*)gamma)[lane];
    float4 b = ((const float4*)beta)[lane];
    float4 o;
    o.x = (v.x - mean) * rstd * g.x + b.x;
    o.y = (v.y - mean) * rstd * g.y + b.y;
    o.z = (v.z - mean) * rstd * g.z + b.z;
    o.w = (v.w - mean) * rstd * g.w + b.w;
    ((float4*)(out + (size_t)i * DIM))[lane] = o;
}

// ---------------- launch ----------------
extern "C" void kernel_launch(void* const* d_in, const int* in_sizes, int n_in,
                              void* d_out, int out_size, void* d_ws, size_t ws_size,
                              hipStream_t stream) {
    const float* x      = (const float*)d_in[0];
    const int*   eidx   = (const int*)d_in[1];
    const float* w_in   = (const float*)d_in[2];
    const float* b_in   = (const float*)d_in[3];
    const float* w_out  = (const float*)d_in[4];
    const float* b_out  = (const float*)d_in[5];
    const float* w_p    = (const float*)d_in[6];
    const float* b_p    = (const float*)d_in[7];
    const float* gamma  = (const float*)d_in[8];
    const float* beta   = (const float*)d_in[9];
    float* out = (float*)d_out;

    char* ws = (char*)d_ws;
    int*            nnz     = (int*)(ws + 0);                     // 16 KB
    int*            cols    = (int*)(ws + 16384);                 // 4 MB
    unsigned short* qkv_bf  = (unsigned short*)(ws + 4210688);    // 6 MB
    unsigned short* ctx_bf  = (unsigned short*)(ws + 10502144);   // 2 MB
    float*          ybuf    = (float*)(ws + 12599296);            // 4 MB
    unsigned short* wc_bf   = (unsigned short*)(ws + 16793600);   // 128 KB
    float*          bc      = (float*)(ws + 16924672);            // 1 KB

    // fused CSR build (zero+scatter+extract in LDS)
    csr_fused_kernel<<<N_NODES / CSR_ROWS, 256, 0, stream>>>(eidx, nnz, cols);
    // Wc = W_p @ W_out (bf16), bc = W_p@b_out + b_p
    {
        dim3 grid(16, 16), blk(16, 16);
        wc_kernel<<<grid, blk, 0, stream>>>(w_p, w_out, b_out, b_p, wc_bf, bc);
    }
    // qkv = x @ w_in^T + b_in -> bf16 [4096 x 768] (both inputs fp32, converted in staging)
    {
        dim3 grid(768 / 128, N_NODES / 128);
        mfma_gemm_bt<true, true, true><<<grid, 256, 0, stream>>>(x, w_in, b_in, nullptr,
                                                                 qkv_bf, N_NODES, 768, DIM);
    }
    // single-pass sparse attention -> ctx bf16 [4096 x 256]
    attn_sparse_kernel<<<N_NODES, 256, 0, stream>>>(qkv_bf, cols, nnz, ctx_bf);
    // y = ctx @ Wc^T + bc + x -> fp32
    {
        dim3 grid(DIM / 128, N_NODES / 128);
        mfma_gemm_bt<false, false, false><<<grid, 256, 0, stream>>>(ctx_bf, wc_bf, bc, x,
                                                                    ybuf, N_NODES, DIM, DIM);
    }
    // LayerNorm -> out
    ln_kernel<<<N_NODES / 4, 256, 0, stream>>>(ybuf, gamma, beta, out);
}

// Round 6
// 163.115 us; speedup vs baseline: 1.3324x; 1.3324x over previous
//
#include <hip/hip_runtime.h>
#include <math.h>

#define N_NODES 4096
#define DIM 256
#define HEADS 4
#define HDIM 64
#define NEDGE 131072
#define MAXNBR 256
#define MASK_WORDS 128   // 4096 / 32

typedef __attribute__((ext_vector_type(8))) short short8;
typedef __attribute__((ext_vector_type(4))) float float4v;

__device__ inline unsigned short f2b(float f) {   // fp32 -> bf16 RNE
    unsigned u = __float_as_uint(f);
    unsigned r = u + 0x7fffu + ((u >> 16) & 1u);
    return (unsigned short)(r >> 16);
}
__device__ inline float b2f(unsigned short s) { return __uint_as_float(((unsigned)s) << 16); }
__device__ inline float bl(unsigned u) { return __uint_as_float(u << 16); }
__device__ inline float bh(unsigned u) { return __uint_as_float(u & 0xffff0000u); }

// ---------------- fp32 -> bf16 conversion ----------------
__global__ void f32_to_bf16_kernel(const float* __restrict__ src,
                                   unsigned short* __restrict__ dst, int n) {
    int t = (blockIdx.x * blockDim.x + threadIdx.x) * 4;
    if (t >= n) return;
    float4 v = *(const float4*)&src[t];
    ushort4 o;
    o.x = f2b(v.x); o.y = f2b(v.y); o.z = f2b(v.z); o.w = f2b(v.w);
    *(ushort4*)&dst[t] = o;
}

// ---------------- mask build (edge-parallel, global atomics, L2-resident) ------
__global__ void build_mask_kernel(const int* __restrict__ eidx, unsigned int* __restrict__ mask) {
    int t = blockIdx.x * blockDim.x + threadIdx.x;
    if (t < NEDGE) {
        int s = eidx[t];
        int d = eidx[NEDGE + t];
        atomicOr(&mask[s * MASK_WORDS + (d >> 5)], 1u << (d & 31));
        atomicOr(&mask[d * MASK_WORDS + (s >> 5)], 1u << (s & 31));
    }
}

// wave-per-row CSR extraction; diag (self-loop) bit folded in.
__global__ __launch_bounds__(256)
void extract_csr_kernel(const unsigned int* __restrict__ mask,
                        int* __restrict__ nnz, int* __restrict__ cols) {
    const int wave = threadIdx.x >> 6;
    const int lane = threadIdx.x & 63;
    const int i = blockIdx.x * 4 + wave;
    const unsigned int* row = mask + (size_t)i * MASK_WORDS;
    unsigned w0 = row[lane * 2];
    unsigned w1 = row[lane * 2 + 1];
    // self-loop bit
    int wi = i >> 5;
    if (wi == lane * 2)     w0 |= 1u << (i & 31);
    if (wi == lane * 2 + 1) w1 |= 1u << (i & 31);
    int cnt = __popc(w0) + __popc(w1);
    int incl = cnt;
#pragma unroll
    for (int off = 1; off < 64; off <<= 1) {
        int v = __shfl_up(incl, off, 64);
        if (lane >= off) incl += v;
    }
    int c = incl - cnt;
    int total = __shfl(incl, 63, 64);
    while (w0) {
        int b = __ffs(w0) - 1;
        if (c < MAXNBR) cols[(size_t)i * MAXNBR + c] = lane * 64 + b;
        ++c; w0 &= w0 - 1u;
    }
    while (w1) {
        int b = __ffs(w1) - 1;
        if (c < MAXNBR) cols[(size_t)i * MAXNBR + c] = lane * 64 + 32 + b;
        ++c; w1 &= w1 - 1u;
    }
    if (lane == 0) nnz[i] = total > MAXNBR ? MAXNBR : total;
}

// ---------------- Wc = W_p @ W_out, bc = W_p@b_out + b_p (4-way ILP) ----------------
__global__ __launch_bounds__(256)
void wc_kernel(const float* __restrict__ wp, const float* __restrict__ wout,
               const float* __restrict__ bout, const float* __restrict__ bp,
               unsigned short* __restrict__ wc, float* __restrict__ bc) {
    const int j = blockIdx.x * 16 + threadIdx.x;
    const int i = blockIdx.y * 16 + threadIdx.y;
    float a0 = 0.f, a1 = 0.f, a2 = 0.f, a3 = 0.f;
    for (int k = 0; k < 256; k += 4) {
        a0 = fmaf(wp[i * 256 + k + 0], wout[(k + 0) * 256 + j], a0);
        a1 = fmaf(wp[i * 256 + k + 1], wout[(k + 1) * 256 + j], a1);
        a2 = fmaf(wp[i * 256 + k + 2], wout[(k + 2) * 256 + j], a2);
        a3 = fmaf(wp[i * 256 + k + 3], wout[(k + 3) * 256 + j], a3);
    }
    wc[i * 256 + j] = f2b((a0 + a1) + (a2 + a3));
    if (blockIdx.x == 0 && blockIdx.y == 0) {
        int t = threadIdx.y * 16 + threadIdx.x;
        float b0 = bp[t], b1 = 0.f, b2 = 0.f, b3 = 0.f;
        for (int k = 0; k < 256; k += 4) {
            b0 = fmaf(wp[t * 256 + k + 0], bout[k + 0], b0);
            b1 = fmaf(wp[t * 256 + k + 1], bout[k + 1], b1);
            b2 = fmaf(wp[t * 256 + k + 2], bout[k + 2], b2);
            b3 = fmaf(wp[t * 256 + k + 3], bout[k + 3], b3);
        }
        bc[t] = (b0 + b1) + (b2 + b3);
    }
}

// ---------------- bf16 MFMA GEMM:  C[M][Nc] = A[M][K] x B[Nc][K]^T + bias (+resid) ----
// BM=BN=128, BK=64, 4 waves (2x2 of 64x64), mfma_f32_16x16x32_bf16, XOR-swizzled LDS.
template <bool OUT_BF16>
__global__ __launch_bounds__(256)
void mfma_gemm_bt(const unsigned short* __restrict__ A, const unsigned short* __restrict__ B,
                  const float* __restrict__ bias, const float* __restrict__ resid,
                  void* __restrict__ Cout, int M, int Nc, int K) {
    __shared__ unsigned short As[128 * 64];
    __shared__ unsigned short Bs[128 * 64];
    const int tid  = threadIdx.x;
    const int lane = tid & 63;
    const int wave = tid >> 6;
    const int wm = wave & 1;
    const int wn = wave >> 1;
    const int brow = blockIdx.y * 128;
    const int bcol = blockIdx.x * 128;

    float4v acc[16];
#pragma unroll
    for (int t = 0; t < 16; ++t) acc[t] = (float4v){0.f, 0.f, 0.f, 0.f};

    const int quad = lane >> 4;
    const int l16  = lane & 15;

    for (int k0 = 0; k0 < K; k0 += 64) {
        __syncthreads();
#pragma unroll
        for (int it = 0; it < 4; ++it) {
            int c = it * 256 + tid;
            int row = c >> 3;
            int col = c & 7;
            int sw  = col ^ (row & 7);
            uint4 va = *(const uint4*)&A[(size_t)(brow + row) * K + k0 + col * 8];
            uint4 vb = *(const uint4*)&B[(size_t)(bcol + row) * K + k0 + col * 8];
            *(uint4*)&As[row * 64 + sw * 8] = va;
            *(uint4*)&Bs[row * 64 + sw * 8] = vb;
        }
        __syncthreads();
#pragma unroll
        for (int kk = 0; kk < 2; ++kk) {
            short8 af[4], bf[4];
#pragma unroll
            for (int mt = 0; mt < 4; ++mt) {
                int row = wm * 64 + mt * 16 + l16;
                int sw = (kk * 4 + quad) ^ (row & 7);
                af[mt] = *(const short8*)&As[row * 64 + sw * 8];
            }
#pragma unroll
            for (int nt = 0; nt < 4; ++nt) {
                int row = wn * 64 + nt * 16 + l16;
                int sw = (kk * 4 + quad) ^ (row & 7);
                bf[nt] = *(const short8*)&Bs[row * 64 + sw * 8];
            }
#pragma unroll
            for (int mt = 0; mt < 4; ++mt)
#pragma unroll
                for (int nt = 0; nt < 4; ++nt)
                    acc[mt * 4 + nt] = __builtin_amdgcn_mfma_f32_16x16x32_bf16(
                        af[mt], bf[nt], acc[mt * 4 + nt], 0, 0, 0);
        }
    }

#pragma unroll
    for (int mt = 0; mt < 4; ++mt) {
#pragma unroll
        for (int nt = 0; nt < 4; ++nt) {
            int colg = bcol + wn * 64 + nt * 16 + l16;
            float bsv = bias[colg];
#pragma unroll
            for (int reg = 0; reg < 4; ++reg) {
                int rowg = brow + wm * 64 + mt * 16 + quad * 4 + reg;
                float v = acc[mt * 4 + nt][reg] + bsv;
                if (resid) v += resid[(size_t)rowg * Nc + colg];
                if (OUT_BF16)
                    ((unsigned short*)Cout)[(size_t)rowg * Nc + colg] = f2b(v);
                else
                    ((float*)Cout)[(size_t)rowg * Nc + colg] = v;
            }
        }
    }
}

// ---------------- single-pass sparse attention (bf16 qkv) ----------------
// Block per query row i; wave = head. lane = (ng 0..7, dg 0..7): 8-lane clusters
// cooperatively process neighbor t0+ng; dg indexes 8-dim octets (16B loads).
// No max-subtraction (|scores| <~ 6, exp safe in fp32): unnormalized accumulate.
__global__ __launch_bounds__(256)
void attn_sparse_kernel(const unsigned short* __restrict__ qkv, const int* __restrict__ cols,
                        const int* __restrict__ nnz, unsigned short* __restrict__ ctx) {
    __shared__ int cols_s[MAXNBR];

    const int wave = threadIdx.x >> 6;   // head
    const int lane = threadIdx.x & 63;
    const int ng = lane >> 3;
    const int dg = lane & 7;
    const int i = blockIdx.x;
    const int h = wave;

    cols_s[threadIdx.x] = cols[(size_t)i * MAXNBR + threadIdx.x];
    int count = nnz[i];
    if (count > MAXNBR) count = MAXNBR;

    float qf[8];
    {
        uint4 qv = *(const uint4*)&qkv[(size_t)i * 768 + h * HDIM + dg * 8];
        qf[0] = bl(qv.x); qf[1] = bh(qv.x);
        qf[2] = bl(qv.y); qf[3] = bh(qv.y);
        qf[4] = bl(qv.z); qf[5] = bh(qv.z);
        qf[6] = bl(qv.w); qf[7] = bh(qv.w);
    }
    __syncthreads();

    const unsigned short* kB = qkv + DIM + h * HDIM + dg * 8;      // K base
    const unsigned short* vB = qkv + 2 * DIM + h * HDIM + dg * 8;  // V base
    float a0 = 0.f, a1 = 0.f, a2 = 0.f, a3 = 0.f, a4 = 0.f, a5 = 0.f, a6 = 0.f, a7 = 0.f;
    float esum = 0.f;

    for (int t0 = 0; t0 < count; t0 += 8) {
        int t = t0 + ng;
        int j = cols_s[min(t, count - 1)];
        uint4 kv = *(const uint4*)&kB[(size_t)j * 768];
        uint4 vv = *(const uint4*)&vB[(size_t)j * 768];
        float s = qf[0] * bl(kv.x) + qf[1] * bh(kv.x)
                + qf[2] * bl(kv.y) + qf[3] * bh(kv.y)
                + qf[4] * bl(kv.z) + qf[5] * bh(kv.z)
                + qf[6] * bl(kv.w) + qf[7] * bh(kv.w);
        s += __shfl_xor(s, 1, 64);
        s += __shfl_xor(s, 2, 64);
        s += __shfl_xor(s, 4, 64);
        float e = (t < count) ? expf(s * 0.125f) : 0.f;
        esum += e;
        a0 = fmaf(e, bl(vv.x), a0); a1 = fmaf(e, bh(vv.x), a1);
        a2 = fmaf(e, bl(vv.y), a2); a3 = fmaf(e, bh(vv.y), a3);
        a4 = fmaf(e, bl(vv.z), a4); a5 = fmaf(e, bh(vv.z), a5);
        a6 = fmaf(e, bl(vv.w), a6); a7 = fmaf(e, bh(vv.w), a7);
    }
#pragma unroll
    for (int off = 8; off <= 32; off <<= 1) {
        esum += __shfl_xor(esum, off, 64);
        a0 += __shfl_xor(a0, off, 64); a1 += __shfl_xor(a1, off, 64);
        a2 += __shfl_xor(a2, off, 64); a3 += __shfl_xor(a3, off, 64);
        a4 += __shfl_xor(a4, off, 64); a5 += __shfl_xor(a5, off, 64);
        a6 += __shfl_xor(a6, off, 64); a7 += __shfl_xor(a7, off, 64);
    }
    if (ng == 0) {
        float inv = 1.0f / esum;
        uint4 w;
        w.x = (unsigned)f2b(a0 * inv) | ((unsigned)f2b(a1 * inv) << 16);
        w.y = (unsigned)f2b(a2 * inv) | ((unsigned)f2b(a3 * inv) << 16);
        w.z = (unsigned)f2b(a4 * inv) | ((unsigned)f2b(a5 * inv) << 16);
        w.w = (unsigned)f2b(a6 * inv) | ((unsigned)f2b(a7 * inv) << 16);
        *(uint4*)&ctx[(size_t)i * DIM + h * HDIM + dg * 8] = w;
    }
}

// ---------------- LayerNorm ----------------
__global__ __launch_bounds__(256)
void ln_kernel(const float* __restrict__ y, const float* __restrict__ gamma,
               const float* __restrict__ beta, float* __restrict__ out) {
    const int wave = threadIdx.x >> 6;
    const int lane = threadIdx.x & 63;
    const int i = blockIdx.x * 4 + wave;
    float4 v = ((const float4*)(y + (size_t)i * DIM))[lane];
    float s = v.x + v.y + v.z + v.w;
    float ss = v.x * v.x + v.y * v.y + v.z * v.z + v.w * v.w;
#pragma unroll
    for (int off = 32; off > 0; off >>= 1) {
        s += __shfl_xor(s, off, 64);
        ss += __shfl_xor(ss, off, 64);
    }
    float mean = s * (1.f / 256.f);
    float var = ss * (1.f / 256.f) - mean * mean;
    float rstd = rsqrtf(var + 1e-5f);
    float4 g = ((const float4*)gamma)[lane];
    float4 b = ((const float4*)beta)[lane];
    float4 o;
    o.x = (v.x - mean) * rstd * g.x + b.x;
    o.y = (v.y - mean) * rstd * g.y + b.y;
    o.z = (v.z - mean) * rstd * g.z + b.z;
    o.w = (v.w - mean) * rstd * g.w + b.w;
    ((float4*)(out + (size_t)i * DIM))[lane] = o;
}

// ---------------- launch ----------------
extern "C" void kernel_launch(void* const* d_in, const int* in_sizes, int n_in,
                              void* d_out, int out_size, void* d_ws, size_t ws_size,
                              hipStream_t stream) {
    const float* x      = (const float*)d_in[0];
    const int*   eidx   = (const int*)d_in[1];
    const float* w_in   = (const float*)d_in[2];
    const float* b_in   = (const float*)d_in[3];
    const float* w_out  = (const float*)d_in[4];
    const float* b_out  = (const float*)d_in[5];
    const float* w_p    = (const float*)d_in[6];
    const float* b_p    = (const float*)d_in[7];
    const float* gamma  = (const float*)d_in[8];
    const float* beta   = (const float*)d_in[9];
    float* out = (float*)d_out;

    char* ws = (char*)d_ws;
    unsigned int*   mask    = (unsigned int*)(ws + 0);            // 2 MB
    int*            nnz     = (int*)(ws + 2097152);               // 16 KB
    int*            cols    = (int*)(ws + 2113536);               // 4 MB
    unsigned short* qkv_bf  = (unsigned short*)(ws + 6307840);    // 6 MB
    unsigned short* ctx_bf  = (unsigned short*)(ws + 12599296);   // 2 MB
    float*          ybuf    = (float*)(ws + 14696448);            // 4 MB
    unsigned short* x_bf    = (unsigned short*)(ws + 18890752);   // 2 MB
    unsigned short* w_in_bf = (unsigned short*)(ws + 20987904);   // 384 KB
    unsigned short* wc_bf   = (unsigned short*)(ws + 21381120);   // 128 KB
    float*          bc      = (float*)(ws + 21512192);            // 1 KB

    // mask zero + edge scatter + CSR extract (diag folded into extract)
    hipMemsetAsync(mask, 0, N_NODES * MASK_WORDS * 4, stream);
    build_mask_kernel<<<(NEDGE + 255) / 256, 256, 0, stream>>>(eidx, mask);
    extract_csr_kernel<<<N_NODES / 4, 256, 0, stream>>>(mask, nnz, cols);
    // conversions
    f32_to_bf16_kernel<<<(N_NODES * DIM / 4 + 255) / 256, 256, 0, stream>>>(x, x_bf, N_NODES * DIM);
    f32_to_bf16_kernel<<<(768 * DIM / 4 + 255) / 256, 256, 0, stream>>>(w_in, w_in_bf, 768 * DIM);
    // Wc = W_p @ W_out (bf16), bc = W_p@b_out + b_p
    {
        dim3 grid(16, 16), blk(16, 16);
        wc_kernel<<<grid, blk, 0, stream>>>(w_p, w_out, b_out, b_p, wc_bf, bc);
    }
    // qkv = x @ w_in^T + b_in -> bf16 [4096 x 768]
    {
        dim3 grid(768 / 128, N_NODES / 128);
        mfma_gemm_bt<true><<<grid, 256, 0, stream>>>(x_bf, w_in_bf, b_in, nullptr,
                                                     qkv_bf, N_NODES, 768, DIM);
    }
    // single-pass sparse attention -> ctx bf16 [4096 x 256]
    attn_sparse_kernel<<<N_NODES, 256, 0, stream>>>(qkv_bf, cols, nnz, ctx_bf);
    // y = ctx @ Wc^T + bc + x -> fp32
    {
        dim3 grid(DIM / 128, N_NODES / 128);
        mfma_gemm_bt<false><<<grid, 256, 0, stream>>>(ctx_bf, wc_bf, bc, x,
                                                      ybuf, N_NODES, DIM, DIM);
    }
    // LayerNorm -> out
    ln_kernel<<<N_NODES / 4, 256, 0, stream>>>(ybuf, gamma, beta, out);
}

// Round 7
// 143.669 us; speedup vs baseline: 1.5128x; 1.1354x over previous
//
#include <hip/hip_runtime.h>
#include <math.h>

#define N_NODES 4096
#define DIM 256
#define HEADS 4
#define HDIM 64
#define NEDGE 131072
#define MAXNBR 256
#define MASK_WORDS 128   // 4096 / 32

typedef __attribute__((ext_vector_type(8))) short short8;
typedef __attribute__((ext_vector_type(4))) float float4v;

__device__ inline unsigned short f2b(float f) {   // fp32 -> bf16 RNE
    unsigned u = __float_as_uint(f);
    unsigned r = u + 0x7fffu + ((u >> 16) & 1u);
    return (unsigned short)(r >> 16);
}
__device__ inline float b2f(unsigned short s) { return __uint_as_float(((unsigned)s) << 16); }
__device__ inline float bl(unsigned u) { return __uint_as_float(u << 16); }
__device__ inline float bh(unsigned u) { return __uint_as_float(u & 0xffff0000u); }

// ---------------- fused prep: x->bf16 | w_in->bf16 | Wc=W_p@W_out, bc ----------------
// blocks 0..1023: convert x (1024 elems each); 1024..1215: convert w_in;
// 1216..1471: wc 16x16 tile each; block 1216 also computes bc.
__global__ __launch_bounds__(256)
void prep_kernel(const float* __restrict__ x, const float* __restrict__ w_in,
                 const float* __restrict__ wp, const float* __restrict__ wout,
                 const float* __restrict__ bout, const float* __restrict__ bp,
                 unsigned short* __restrict__ x_bf, unsigned short* __restrict__ w_in_bf,
                 unsigned short* __restrict__ wc, float* __restrict__ bc) {
    const int b = blockIdx.x;
    const int tid = threadIdx.x;
    if (b < 1024) {
        int t = b * 1024 + tid * 4;
        float4 v = *(const float4*)&x[t];
        ushort4 o;
        o.x = f2b(v.x); o.y = f2b(v.y); o.z = f2b(v.z); o.w = f2b(v.w);
        *(ushort4*)&x_bf[t] = o;
    } else if (b < 1024 + 192) {
        int t = (b - 1024) * 1024 + tid * 4;
        float4 v = *(const float4*)&w_in[t];
        ushort4 o;
        o.x = f2b(v.x); o.y = f2b(v.y); o.z = f2b(v.z); o.w = f2b(v.w);
        *(ushort4*)&w_in_bf[t] = o;
    } else {
        int bb = b - 1216;               // 0..255
        int i = (bb >> 4) * 16 + (tid >> 4);
        int j = (bb & 15) * 16 + (tid & 15);
        float a0 = 0.f, a1 = 0.f, a2 = 0.f, a3 = 0.f;
        for (int k = 0; k < 256; k += 4) {
            a0 = fmaf(wp[i * 256 + k + 0], wout[(k + 0) * 256 + j], a0);
            a1 = fmaf(wp[i * 256 + k + 1], wout[(k + 1) * 256 + j], a1);
            a2 = fmaf(wp[i * 256 + k + 2], wout[(k + 2) * 256 + j], a2);
            a3 = fmaf(wp[i * 256 + k + 3], wout[(k + 3) * 256 + j], a3);
        }
        wc[i * 256 + j] = f2b((a0 + a1) + (a2 + a3));
        if (bb == 0) {
            float b0 = bp[tid], b1 = 0.f, b2 = 0.f, b3 = 0.f;
            for (int k = 0; k < 256; k += 4) {
                b0 = fmaf(wp[tid * 256 + k + 0], bout[k + 0], b0);
                b1 = fmaf(wp[tid * 256 + k + 1], bout[k + 1], b1);
                b2 = fmaf(wp[tid * 256 + k + 2], bout[k + 2], b2);
                b3 = fmaf(wp[tid * 256 + k + 3], bout[k + 3], b3);
            }
            bc[tid] = (b0 + b1) + (b2 + b3);
        }
    }
}

// ---------------- mask build (edge-parallel, global atomics, L2-resident) ------
__global__ void build_mask_kernel(const int* __restrict__ eidx, unsigned int* __restrict__ mask) {
    int t = blockIdx.x * blockDim.x + threadIdx.x;
    if (t < NEDGE) {
        int s = eidx[t];
        int d = eidx[NEDGE + t];
        atomicOr(&mask[s * MASK_WORDS + (d >> 5)], 1u << (d & 31));
        atomicOr(&mask[d * MASK_WORDS + (s >> 5)], 1u << (s & 31));
    }
}

// wave-per-row CSR extraction; diag (self-loop) bit folded in.
__global__ __launch_bounds__(256)
void extract_csr_kernel(const unsigned int* __restrict__ mask,
                        int* __restrict__ nnz, int* __restrict__ cols) {
    const int wave = threadIdx.x >> 6;
    const int lane = threadIdx.x & 63;
    const int i = blockIdx.x * 4 + wave;
    const unsigned int* row = mask + (size_t)i * MASK_WORDS;
    unsigned w0 = row[lane * 2];
    unsigned w1 = row[lane * 2 + 1];
    int wi = i >> 5;
    if (wi == lane * 2)     w0 |= 1u << (i & 31);
    if (wi == lane * 2 + 1) w1 |= 1u << (i & 31);
    int cnt = __popc(w0) + __popc(w1);
    int incl = cnt;
#pragma unroll
    for (int off = 1; off < 64; off <<= 1) {
        int v = __shfl_up(incl, off, 64);
        if (lane >= off) incl += v;
    }
    int c = incl - cnt;
    int total = __shfl(incl, 63, 64);
    while (w0) {
        int b = __ffs(w0) - 1;
        if (c < MAXNBR) cols[(size_t)i * MAXNBR + c] = lane * 64 + b;
        ++c; w0 &= w0 - 1u;
    }
    while (w1) {
        int b = __ffs(w1) - 1;
        if (c < MAXNBR) cols[(size_t)i * MAXNBR + c] = lane * 64 + 32 + b;
        ++c; w1 &= w1 - 1u;
    }
    if (lane == 0) nnz[i] = total > MAXNBR ? MAXNBR : total;
}

// ---------------- bf16 MFMA GEMM, BM=64, BN=64, BK=64 ----------------
// 4 waves stacked over M (wave w: rows w*16..w*16+16), each wave 1x4 MFMA tiles.
// C[M][Nc] = A[M][K] x B[Nc][K]^T + bias (+resid). XOR-swizzled LDS.
template <bool OUT_BF16>
__global__ __launch_bounds__(256)
void mfma_gemm64(const unsigned short* __restrict__ A, const unsigned short* __restrict__ B,
                 const float* __restrict__ bias, const float* __restrict__ resid,
                 void* __restrict__ Cout, int M, int Nc, int K) {
    __shared__ unsigned short As[64 * 64];
    __shared__ unsigned short Bs[64 * 64];
    const int tid  = threadIdx.x;
    const int lane = tid & 63;
    const int wave = tid >> 6;
    const int brow = blockIdx.y * 64;
    const int bcol = blockIdx.x * 64;

    float4v acc[4];
#pragma unroll
    for (int t = 0; t < 4; ++t) acc[t] = (float4v){0.f, 0.f, 0.f, 0.f};

    const int quad = lane >> 4;
    const int l16  = lane & 15;

    for (int k0 = 0; k0 < K; k0 += 64) {
        __syncthreads();
#pragma unroll
        for (int it = 0; it < 2; ++it) {
            int c = it * 256 + tid;
            int row = c >> 3;
            int col = c & 7;
            int sw  = col ^ (row & 7);
            uint4 va = *(const uint4*)&A[(size_t)(brow + row) * K + k0 + col * 8];
            uint4 vb = *(const uint4*)&B[(size_t)(bcol + row) * K + k0 + col * 8];
            *(uint4*)&As[row * 64 + sw * 8] = va;
            *(uint4*)&Bs[row * 64 + sw * 8] = vb;
        }
        __syncthreads();
#pragma unroll
        for (int kk = 0; kk < 2; ++kk) {
            short8 af, bf[4];
            {
                int row = wave * 16 + l16;
                int sw = (kk * 4 + quad) ^ (row & 7);
                af = *(const short8*)&As[row * 64 + sw * 8];
            }
#pragma unroll
            for (int nt = 0; nt < 4; ++nt) {
                int row = nt * 16 + l16;
                int sw = (kk * 4 + quad) ^ (row & 7);
                bf[nt] = *(const short8*)&Bs[row * 64 + sw * 8];
            }
#pragma unroll
            for (int nt = 0; nt < 4; ++nt)
                acc[nt] = __builtin_amdgcn_mfma_f32_16x16x32_bf16(af, bf[nt], acc[nt], 0, 0, 0);
        }
    }

#pragma unroll
    for (int nt = 0; nt < 4; ++nt) {
        int colg = bcol + nt * 16 + l16;
        float bsv = bias[colg];
#pragma unroll
        for (int reg = 0; reg < 4; ++reg) {
            int rowg = brow + wave * 16 + quad * 4 + reg;
            float v = acc[nt][reg] + bsv;
            if (resid) v += resid[(size_t)rowg * Nc + colg];
            if (OUT_BF16)
                ((unsigned short*)Cout)[(size_t)rowg * Nc + colg] = f2b(v);
            else
                ((float*)Cout)[(size_t)rowg * Nc + colg] = v;
        }
    }
}

// ---------------- single-pass sparse attention (bf16 qkv) ----------------
__global__ __launch_bounds__(256)
void attn_sparse_kernel(const unsigned short* __restrict__ qkv, const int* __restrict__ cols,
                        const int* __restrict__ nnz, unsigned short* __restrict__ ctx) {
    __shared__ int cols_s[MAXNBR];

    const int wave = threadIdx.x >> 6;   // head
    const int lane = threadIdx.x & 63;
    const int ng = lane >> 3;
    const int dg = lane & 7;
    const int i = blockIdx.x;
    const int h = wave;

    cols_s[threadIdx.x] = cols[(size_t)i * MAXNBR + threadIdx.x];
    int count = nnz[i];
    if (count > MAXNBR) count = MAXNBR;

    float qf[8];
    {
        uint4 qv = *(const uint4*)&qkv[(size_t)i * 768 + h * HDIM + dg * 8];
        qf[0] = bl(qv.x); qf[1] = bh(qv.x);
        qf[2] = bl(qv.y); qf[3] = bh(qv.y);
        qf[4] = bl(qv.z); qf[5] = bh(qv.z);
        qf[6] = bl(qv.w); qf[7] = bh(qv.w);
    }
    __syncthreads();

    const unsigned short* kB = qkv + DIM + h * HDIM + dg * 8;
    const unsigned short* vB = qkv + 2 * DIM + h * HDIM + dg * 8;
    float a0 = 0.f, a1 = 0.f, a2 = 0.f, a3 = 0.f, a4 = 0.f, a5 = 0.f, a6 = 0.f, a7 = 0.f;
    float esum = 0.f;

    for (int t0 = 0; t0 < count; t0 += 8) {
        int t = t0 + ng;
        int j = cols_s[min(t, count - 1)];
        uint4 kv = *(const uint4*)&kB[(size_t)j * 768];
        uint4 vv = *(const uint4*)&vB[(size_t)j * 768];
        float s = qf[0] * bl(kv.x) + qf[1] * bh(kv.x)
                + qf[2] * bl(kv.y) + qf[3] * bh(kv.y)
                + qf[4] * bl(kv.z) + qf[5] * bh(kv.z)
                + qf[6] * bl(kv.w) + qf[7] * bh(kv.w);
        s += __shfl_xor(s, 1, 64);
        s += __shfl_xor(s, 2, 64);
        s += __shfl_xor(s, 4, 64);
        float e = (t < count) ? expf(s * 0.125f) : 0.f;
        esum += e;
        a0 = fmaf(e, bl(vv.x), a0); a1 = fmaf(e, bh(vv.x), a1);
        a2 = fmaf(e, bl(vv.y), a2); a3 = fmaf(e, bh(vv.y), a3);
        a4 = fmaf(e, bl(vv.z), a4); a5 = fmaf(e, bh(vv.z), a5);
        a6 = fmaf(e, bl(vv.w), a6); a7 = fmaf(e, bh(vv.w), a7);
    }
#pragma unroll
    for (int off = 8; off <= 32; off <<= 1) {
        esum += __shfl_xor(esum, off, 64);
        a0 += __shfl_xor(a0, off, 64); a1 += __shfl_xor(a1, off, 64);
        a2 += __shfl_xor(a2, off, 64); a3 += __shfl_xor(a3, off, 64);
        a4 += __shfl_xor(a4, off, 64); a5 += __shfl_xor(a5, off, 64);
        a6 += __shfl_xor(a6, off, 64); a7 += __shfl_xor(a7, off, 64);
    }
    if (ng == 0) {
        float inv = 1.0f / esum;
        uint4 w;
        w.x = (unsigned)f2b(a0 * inv) | ((unsigned)f2b(a1 * inv) << 16);
        w.y = (unsigned)f2b(a2 * inv) | ((unsigned)f2b(a3 * inv) << 16);
        w.z = (unsigned)f2b(a4 * inv) | ((unsigned)f2b(a5 * inv) << 16);
        w.w = (unsigned)f2b(a6 * inv) | ((unsigned)f2b(a7 * inv) << 16);
        *(uint4*)&ctx[(size_t)i * DIM + h * HDIM + dg * 8] = w;
    }
}

// ---------------- LayerNorm ----------------
__global__ __launch_bounds__(256)
void ln_kernel(const float* __restrict__ y, const float* __restrict__ gamma,
               const float* __restrict__ beta, float* __restrict__ out) {
    const int wave = threadIdx.x >> 6;
    const int lane = threadIdx.x & 63;
    const int i = blockIdx.x * 4 + wave;
    float4 v = ((const float4*)(y + (size_t)i * DIM))[lane];
    float s = v.x + v.y + v.z + v.w;
    float ss = v.x * v.x + v.y * v.y + v.z * v.z + v.w * v.w;
#pragma unroll
    for (int off = 32; off > 0; off >>= 1) {
        s += __shfl_xor(s, off, 64);
        ss += __shfl_xor(ss, off, 64);
    }
    float mean = s * (1.f / 256.f);
    float var = ss * (1.f / 256.f) - mean * mean;
    float rstd = rsqrtf(var + 1e-5f);
    float4 g = ((const float4*)gamma)[lane];
    float4 b = ((const float4*)beta)[lane];
    float4 o;
    o.x = (v.x - mean) * rstd * g.x + b.x;
    o.y = (v.y - mean) * rstd * g.y + b.y;
    o.z = (v.z - mean) * rstd * g.z + b.z;
    o.w = (v.w - mean) * rstd * g.w + b.w;
    ((float4*)(out + (size_t)i * DIM))[lane] = o;
}

// ---------------- launch ----------------
extern "C" void kernel_launch(void* const* d_in, const int* in_sizes, int n_in,
                              void* d_out, int out_size, void* d_ws, size_t ws_size,
                              hipStream_t stream) {
    const float* x      = (const float*)d_in[0];
    const int*   eidx   = (const int*)d_in[1];
    const float* w_in   = (const float*)d_in[2];
    const float* b_in   = (const float*)d_in[3];
    const float* w_out  = (const float*)d_in[4];
    const float* b_out  = (const float*)d_in[5];
    const float* w_p    = (const float*)d_in[6];
    const float* b_p    = (const float*)d_in[7];
    const float* gamma  = (const float*)d_in[8];
    const float* beta   = (const float*)d_in[9];
    float* out = (float*)d_out;

    char* ws = (char*)d_ws;
    unsigned int*   mask    = (unsigned int*)(ws + 0);            // 2 MB
    int*            nnz     = (int*)(ws + 2097152);               // 16 KB
    int*            cols    = (int*)(ws + 2113536);               // 4 MB
    unsigned short* qkv_bf  = (unsigned short*)(ws + 6307840);    // 6 MB
    unsigned short* ctx_bf  = (unsigned short*)(ws + 12599296);   // 2 MB
    float*          ybuf    = (float*)(ws + 14696448);            // 4 MB
    unsigned short* x_bf    = (unsigned short*)(ws + 18890752);   // 2 MB
    unsigned short* w_in_bf = (unsigned short*)(ws + 20987904);   // 384 KB
    unsigned short* wc_bf   = (unsigned short*)(ws + 21381120);   // 128 KB
    float*          bc      = (float*)(ws + 21512192);            // 1 KB

    // fused prep: converts + Wc/bc (1472 blocks)
    prep_kernel<<<1472, 256, 0, stream>>>(x, w_in, w_p, w_out, b_out, b_p,
                                          x_bf, w_in_bf, wc_bf, bc);
    // mask zero + edge scatter + CSR extract
    hipMemsetAsync(mask, 0, N_NODES * MASK_WORDS * 4, stream);
    build_mask_kernel<<<(NEDGE + 255) / 256, 256, 0, stream>>>(eidx, mask);
    extract_csr_kernel<<<N_NODES / 4, 256, 0, stream>>>(mask, nnz, cols);
    // qkv = x @ w_in^T + b_in -> bf16 [4096 x 768]
    {
        dim3 grid(768 / 64, N_NODES / 64);
        mfma_gemm64<true><<<grid, 256, 0, stream>>>(x_bf, w_in_bf, b_in, nullptr,
                                                    qkv_bf, N_NODES, 768, DIM);
    }
    // single-pass sparse attention -> ctx bf16 [4096 x 256]
    attn_sparse_kernel<<<N_NODES, 256, 0, stream>>>(qkv_bf, cols, nnz, ctx_bf);
    // y = ctx @ Wc^T + bc + x -> fp32
    {
        dim3 grid(DIM / 64, N_NODES / 64);
        mfma_gemm64<false><<<grid, 256, 0, stream>>>(ctx_bf, wc_bf, bc, x,
                                                     ybuf, N_NODES, DIM, DIM);
    }
    // LayerNorm -> out
    ln_kernel<<<N_NODES / 4, 256, 0, stream>>>(ybuf, gamma, beta, out);
}

// Round 8
// 141.659 us; speedup vs baseline: 1.5342x; 1.0142x over previous
//
#include <hip/hip_runtime.h>
#include <math.h>

#define N_NODES 4096
#define DIM 256
#define HEADS 4
#define HDIM 64
#define NEDGE 131072
#define MAXNBR 256
#define MASK_WORDS 128   // 4096 / 32

typedef __attribute__((ext_vector_type(8))) short short8;
typedef __attribute__((ext_vector_type(4))) float float4v;

__device__ inline unsigned short f2b(float f) {   // fp32 -> bf16 RNE
    unsigned u = __float_as_uint(f);
    unsigned r = u + 0x7fffu + ((u >> 16) & 1u);
    return (unsigned short)(r >> 16);
}
__device__ inline float b2f(unsigned short s) { return __uint_as_float(((unsigned)s) << 16); }
__device__ inline float bl(unsigned u) { return __uint_as_float(u << 16); }
__device__ inline float bh(unsigned u) { return __uint_as_float(u & 0xffff0000u); }

// ---------------- fused prep: x->bf16 | w_in->bf16 | Wc=W_p@W_out, bc ----------------
__global__ __launch_bounds__(256)
void prep_kernel(const float* __restrict__ x, const float* __restrict__ w_in,
                 const float* __restrict__ wp, const float* __restrict__ wout,
                 const float* __restrict__ bout, const float* __restrict__ bp,
                 unsigned short* __restrict__ x_bf, unsigned short* __restrict__ w_in_bf,
                 unsigned short* __restrict__ wc, float* __restrict__ bc) {
    const int b = blockIdx.x;
    const int tid = threadIdx.x;
    if (b < 1024) {
        int t = b * 1024 + tid * 4;
        float4 v = *(const float4*)&x[t];
        ushort4 o;
        o.x = f2b(v.x); o.y = f2b(v.y); o.z = f2b(v.z); o.w = f2b(v.w);
        *(ushort4*)&x_bf[t] = o;
    } else if (b < 1024 + 192) {
        int t = (b - 1024) * 1024 + tid * 4;
        float4 v = *(const float4*)&w_in[t];
        ushort4 o;
        o.x = f2b(v.x); o.y = f2b(v.y); o.z = f2b(v.z); o.w = f2b(v.w);
        *(ushort4*)&w_in_bf[t] = o;
    } else {
        int bb = b - 1216;               // 0..255
        int i = (bb >> 4) * 16 + (tid >> 4);
        int j = (bb & 15) * 16 + (tid & 15);
        float a0 = 0.f, a1 = 0.f, a2 = 0.f, a3 = 0.f;
        for (int k = 0; k < 256; k += 4) {
            a0 = fmaf(wp[i * 256 + k + 0], wout[(k + 0) * 256 + j], a0);
            a1 = fmaf(wp[i * 256 + k + 1], wout[(k + 1) * 256 + j], a1);
            a2 = fmaf(wp[i * 256 + k + 2], wout[(k + 2) * 256 + j], a2);
            a3 = fmaf(wp[i * 256 + k + 3], wout[(k + 3) * 256 + j], a3);
        }
        wc[i * 256 + j] = f2b((a0 + a1) + (a2 + a3));
        if (bb == 0) {
            float b0 = bp[tid], b1 = 0.f, b2 = 0.f, b3 = 0.f;
            for (int k = 0; k < 256; k += 4) {
                b0 = fmaf(wp[tid * 256 + k + 0], bout[k + 0], b0);
                b1 = fmaf(wp[tid * 256 + k + 1], bout[k + 1], b1);
                b2 = fmaf(wp[tid * 256 + k + 2], bout[k + 2], b2);
                b3 = fmaf(wp[tid * 256 + k + 3], bout[k + 3], b3);
            }
            bc[tid] = (b0 + b1) + (b2 + b3);
        }
    }
}

// ---------------- mask build (edge-parallel, global atomics, L2-resident) ------
__global__ void build_mask_kernel(const int* __restrict__ eidx, unsigned int* __restrict__ mask) {
    int t = blockIdx.x * blockDim.x + threadIdx.x;
    if (t < NEDGE) {
        int s = eidx[t];
        int d = eidx[NEDGE + t];
        atomicOr(&mask[s * MASK_WORDS + (d >> 5)], 1u << (d & 31));
        atomicOr(&mask[d * MASK_WORDS + (s >> 5)], 1u << (s & 31));
    }
}

// ---------------- bf16 MFMA GEMM, BM=64, BN=64, BK=64 ----------------
template <bool OUT_BF16>
__global__ __launch_bounds__(256)
void mfma_gemm64(const unsigned short* __restrict__ A, const unsigned short* __restrict__ B,
                 const float* __restrict__ bias, const float* __restrict__ resid,
                 void* __restrict__ Cout, int M, int Nc, int K) {
    __shared__ unsigned short As[64 * 64];
    __shared__ unsigned short Bs[64 * 64];
    const int tid  = threadIdx.x;
    const int lane = tid & 63;
    const int wave = tid >> 6;
    const int brow = blockIdx.y * 64;
    const int bcol = blockIdx.x * 64;

    float4v acc[4];
#pragma unroll
    for (int t = 0; t < 4; ++t) acc[t] = (float4v){0.f, 0.f, 0.f, 0.f};

    const int quad = lane >> 4;
    const int l16  = lane & 15;

    for (int k0 = 0; k0 < K; k0 += 64) {
        __syncthreads();
#pragma unroll
        for (int it = 0; it < 2; ++it) {
            int c = it * 256 + tid;
            int row = c >> 3;
            int col = c & 7;
            int sw  = col ^ (row & 7);
            uint4 va = *(const uint4*)&A[(size_t)(brow + row) * K + k0 + col * 8];
            uint4 vb = *(const uint4*)&B[(size_t)(bcol + row) * K + k0 + col * 8];
            *(uint4*)&As[row * 64 + sw * 8] = va;
            *(uint4*)&Bs[row * 64 + sw * 8] = vb;
        }
        __syncthreads();
#pragma unroll
        for (int kk = 0; kk < 2; ++kk) {
            short8 af, bf[4];
            {
                int row = wave * 16 + l16;
                int sw = (kk * 4 + quad) ^ (row & 7);
                af = *(const short8*)&As[row * 64 + sw * 8];
            }
#pragma unroll
            for (int nt = 0; nt < 4; ++nt) {
                int row = nt * 16 + l16;
                int sw = (kk * 4 + quad) ^ (row & 7);
                bf[nt] = *(const short8*)&Bs[row * 64 + sw * 8];
            }
#pragma unroll
            for (int nt = 0; nt < 4; ++nt)
                acc[nt] = __builtin_amdgcn_mfma_f32_16x16x32_bf16(af, bf[nt], acc[nt], 0, 0, 0);
        }
    }

#pragma unroll
    for (int nt = 0; nt < 4; ++nt) {
        int colg = bcol + nt * 16 + l16;
        float bsv = bias[colg];
#pragma unroll
        for (int reg = 0; reg < 4; ++reg) {
            int rowg = brow + wave * 16 + quad * 4 + reg;
            float v = acc[nt][reg] + bsv;
            if (resid) v += resid[(size_t)rowg * Nc + colg];
            if (OUT_BF16)
                ((unsigned short*)Cout)[(size_t)rowg * Nc + colg] = f2b(v);
            else
                ((float*)Cout)[(size_t)rowg * Nc + colg] = v;
        }
    }
}

// ---------------- single-pass sparse attention with in-block CSR extraction ----
// Block per query row i; wave = head. Wave 0 extracts the neighbor list from the
// bitmask row (512 B) while other waves wait; main loop: lane=(ng,dg), 2 neighbors
// per lane per iter (16/iter), 4x16B loads in flight, shfl-reduced dots, fused
// exp+accumulate (no max-subtraction: |s|<~6, fp32 exp safe).
__global__ __launch_bounds__(256)
void attn_sparse_kernel(const unsigned short* __restrict__ qkv,
                        const unsigned int* __restrict__ mask,
                        unsigned short* __restrict__ ctx) {
    __shared__ unsigned int rowmask[MASK_WORDS];
    __shared__ int cols_s[MAXNBR];
    __shared__ int count_s;

    const int tid  = threadIdx.x;
    const int wave = tid >> 6;   // head
    const int lane = tid & 63;
    const int ng = lane >> 3;
    const int dg = lane & 7;
    const int i = blockIdx.x;
    const int h = wave;

    if (tid < MASK_WORDS) rowmask[tid] = mask[(size_t)i * MASK_WORDS + tid];

    float qf[8];
    {
        uint4 qv = *(const uint4*)&qkv[(size_t)i * 768 + h * HDIM + dg * 8];
        qf[0] = bl(qv.x); qf[1] = bh(qv.x);
        qf[2] = bl(qv.y); qf[3] = bh(qv.y);
        qf[4] = bl(qv.z); qf[5] = bh(qv.z);
        qf[6] = bl(qv.w); qf[7] = bh(qv.w);
    }
    __syncthreads();

    if (wave == 0) {
        unsigned w0 = rowmask[lane * 2];
        unsigned w1 = rowmask[lane * 2 + 1];
        int wi = i >> 5;
        if (wi == lane * 2)     w0 |= 1u << (i & 31);   // self-loop
        if (wi == lane * 2 + 1) w1 |= 1u << (i & 31);
        int cnt = __popc(w0) + __popc(w1);
        int incl = cnt;
#pragma unroll
        for (int off = 1; off < 64; off <<= 1) {
            int v = __shfl_up(incl, off, 64);
            if (lane >= off) incl += v;
        }
        int c = incl - cnt;
        int total = __shfl(incl, 63, 64);
        while (w0) {
            int b = __ffs(w0) - 1;
            if (c < MAXNBR) cols_s[c] = lane * 64 + b;
            ++c; w0 &= w0 - 1u;
        }
        while (w1) {
            int b = __ffs(w1) - 1;
            if (c < MAXNBR) cols_s[c] = lane * 64 + 32 + b;
            ++c; w1 &= w1 - 1u;
        }
        if (lane == 0) count_s = total > MAXNBR ? MAXNBR : total;
    }
    __syncthreads();
    const int count = count_s;

    const unsigned short* kB = qkv + DIM + h * HDIM + dg * 8;
    const unsigned short* vB = qkv + 2 * DIM + h * HDIM + dg * 8;
    float a0 = 0.f, a1 = 0.f, a2 = 0.f, a3 = 0.f, a4 = 0.f, a5 = 0.f, a6 = 0.f, a7 = 0.f;
    float esum = 0.f;

    for (int t0 = 0; t0 < count; t0 += 16) {
        int tA = t0 + ng;
        int tB = t0 + 8 + ng;
        int jA = cols_s[min(tA, count - 1)];
        int jB = cols_s[min(tB, count - 1)];
        uint4 kvA = *(const uint4*)&kB[(size_t)jA * 768];
        uint4 vvA = *(const uint4*)&vB[(size_t)jA * 768];
        uint4 kvB = *(const uint4*)&kB[(size_t)jB * 768];
        uint4 vvB = *(const uint4*)&vB[(size_t)jB * 768];
        float sA = qf[0] * bl(kvA.x) + qf[1] * bh(kvA.x)
                 + qf[2] * bl(kvA.y) + qf[3] * bh(kvA.y)
                 + qf[4] * bl(kvA.z) + qf[5] * bh(kvA.z)
                 + qf[6] * bl(kvA.w) + qf[7] * bh(kvA.w);
        float sB = qf[0] * bl(kvB.x) + qf[1] * bh(kvB.x)
                 + qf[2] * bl(kvB.y) + qf[3] * bh(kvB.y)
                 + qf[4] * bl(kvB.z) + qf[5] * bh(kvB.z)
                 + qf[6] * bl(kvB.w) + qf[7] * bh(kvB.w);
        sA += __shfl_xor(sA, 1, 64);  sB += __shfl_xor(sB, 1, 64);
        sA += __shfl_xor(sA, 2, 64);  sB += __shfl_xor(sB, 2, 64);
        sA += __shfl_xor(sA, 4, 64);  sB += __shfl_xor(sB, 4, 64);
        float eA = (tA < count) ? expf(sA * 0.125f) : 0.f;
        float eB = (tB < count) ? expf(sB * 0.125f) : 0.f;
        esum += eA + eB;
        a0 = fmaf(eA, bl(vvA.x), a0); a1 = fmaf(eA, bh(vvA.x), a1);
        a2 = fmaf(eA, bl(vvA.y), a2); a3 = fmaf(eA, bh(vvA.y), a3);
        a4 = fmaf(eA, bl(vvA.z), a4); a5 = fmaf(eA, bh(vvA.z), a5);
        a6 = fmaf(eA, bl(vvA.w), a6); a7 = fmaf(eA, bh(vvA.w), a7);
        a0 = fmaf(eB, bl(vvB.x), a0); a1 = fmaf(eB, bh(vvB.x), a1);
        a2 = fmaf(eB, bl(vvB.y), a2); a3 = fmaf(eB, bh(vvB.y), a3);
        a4 = fmaf(eB, bl(vvB.z), a4); a5 = fmaf(eB, bh(vvB.z), a5);
        a6 = fmaf(eB, bl(vvB.w), a6); a7 = fmaf(eB, bh(vvB.w), a7);
    }
#pragma unroll
    for (int off = 8; off <= 32; off <<= 1) {
        esum += __shfl_xor(esum, off, 64);
        a0 += __shfl_xor(a0, off, 64); a1 += __shfl_xor(a1, off, 64);
        a2 += __shfl_xor(a2, off, 64); a3 += __shfl_xor(a3, off, 64);
        a4 += __shfl_xor(a4, off, 64); a5 += __shfl_xor(a5, off, 64);
        a6 += __shfl_xor(a6, off, 64); a7 += __shfl_xor(a7, off, 64);
    }
    if (ng == 0) {
        float inv = 1.0f / esum;
        uint4 w;
        w.x = (unsigned)f2b(a0 * inv) | ((unsigned)f2b(a1 * inv) << 16);
        w.y = (unsigned)f2b(a2 * inv) | ((unsigned)f2b(a3 * inv) << 16);
        w.z = (unsigned)f2b(a4 * inv) | ((unsigned)f2b(a5 * inv) << 16);
        w.w = (unsigned)f2b(a6 * inv) | ((unsigned)f2b(a7 * inv) << 16);
        *(uint4*)&ctx[(size_t)i * DIM + h * HDIM + dg * 8] = w;
    }
}

// ---------------- LayerNorm ----------------
__global__ __launch_bounds__(256)
void ln_kernel(const float* __restrict__ y, const float* __restrict__ gamma,
               const float* __restrict__ beta, float* __restrict__ out) {
    const int wave = threadIdx.x >> 6;
    const int lane = threadIdx.x & 63;
    const int i = blockIdx.x * 4 + wave;
    float4 v = ((const float4*)(y + (size_t)i * DIM))[lane];
    float s = v.x + v.y + v.z + v.w;
    float ss = v.x * v.x + v.y * v.y + v.z * v.z + v.w * v.w;
#pragma unroll
    for (int off = 32; off > 0; off >>= 1) {
        s += __shfl_xor(s, off, 64);
        ss += __shfl_xor(ss, off, 64);
    }
    float mean = s * (1.f / 256.f);
    float var = ss * (1.f / 256.f) - mean * mean;
    float rstd = rsqrtf(var + 1e-5f);
    float4 g = ((const float4*)gamma)[lane];
    float4 b = ((const float4*)beta)[lane];
    float4 o;
    o.x = (v.x - mean) * rstd * g.x + b.x;
    o.y = (v.y - mean) * rstd * g.y + b.y;
    o.z = (v.z - mean) * rstd * g.z + b.z;
    o.w = (v.w - mean) * rstd * g.w + b.w;
    ((float4*)(out + (size_t)i * DIM))[lane] = o;
}

// ---------------- launch ----------------
extern "C" void kernel_launch(void* const* d_in, const int* in_sizes, int n_in,
                              void* d_out, int out_size, void* d_ws, size_t ws_size,
                              hipStream_t stream) {
    const float* x      = (const float*)d_in[0];
    const int*   eidx   = (const int*)d_in[1];
    const float* w_in   = (const float*)d_in[2];
    const float* b_in   = (const float*)d_in[3];
    const float* w_out  = (const float*)d_in[4];
    const float* b_out  = (const float*)d_in[5];
    const float* w_p    = (const float*)d_in[6];
    const float* b_p    = (const float*)d_in[7];
    const float* gamma  = (const float*)d_in[8];
    const float* beta   = (const float*)d_in[9];
    float* out = (float*)d_out;

    char* ws = (char*)d_ws;
    unsigned int*   mask    = (unsigned int*)(ws + 0);            // 2 MB
    unsigned short* qkv_bf  = (unsigned short*)(ws + 2097152);    // 6 MB
    unsigned short* ctx_bf  = (unsigned short*)(ws + 8388608);    // 2 MB
    float*          ybuf    = (float*)(ws + 10485760);            // 4 MB
    unsigned short* x_bf    = (unsigned short*)(ws + 14680064);   // 2 MB
    unsigned short* w_in_bf = (unsigned short*)(ws + 16777216);   // 384 KB
    unsigned short* wc_bf   = (unsigned short*)(ws + 17170432);   // 128 KB
    float*          bc      = (float*)(ws + 17301504);            // 1 KB

    // fused prep: converts + Wc/bc
    prep_kernel<<<1472, 256, 0, stream>>>(x, w_in, w_p, w_out, b_out, b_p,
                                          x_bf, w_in_bf, wc_bf, bc);
    // mask zero + edge scatter (CSR extraction folded into attention)
    hipMemsetAsync(mask, 0, N_NODES * MASK_WORDS * 4, stream);
    build_mask_kernel<<<(NEDGE + 255) / 256, 256, 0, stream>>>(eidx, mask);
    // qkv = x @ w_in^T + b_in -> bf16 [4096 x 768]
    {
        dim3 grid(768 / 64, N_NODES / 64);
        mfma_gemm64<true><<<grid, 256, 0, stream>>>(x_bf, w_in_bf, b_in, nullptr,
                                                    qkv_bf, N_NODES, 768, DIM);
    }
    // sparse attention (in-block CSR) -> ctx bf16 [4096 x 256]
    attn_sparse_kernel<<<N_NODES, 256, 0, stream>>>(qkv_bf, mask, ctx_bf);
    // y = ctx @ Wc^T + bc + x -> fp32
    {
        dim3 grid(DIM / 64, N_NODES / 64);
        mfma_gemm64<false><<<grid, 256, 0, stream>>>(ctx_bf, wc_bf, bc, x,
                                                     ybuf, N_NODES, DIM, DIM);
    }
    // LayerNorm -> out
    ln_kernel<<<N_NODES / 4, 256, 0, stream>>>(ybuf, gamma, beta, out);
}